// Round 7
// baseline (564.950 us; speedup 1.0000x reference)
//
#include <hip/hip_runtime.h>
#include <hip/hip_bf16.h>
#include <math.h>

// Problem dims
#define NB 256
#define NT 512
#define NF 128
#define NCOH 64         // coh_pts
#define NIN 192         // F + coh_pts
#define NBS 384         // 3*bulk_pts
#define NROWS (NB*NT)   // 131072

// Material constants (match fp64->fp32 of reference)
#define C11 1098.9010989010989f
#define C12 329.67032967032966f
#define C33 384.61538461538464f
#define H3G 1253.8461538461538f   // 3*G + HARD

typedef __attribute__((ext_vector_type(8))) short bf16x8;   // 8 bf16 = 4 VGPR
typedef __attribute__((ext_vector_type(4))) float f32x4;    // MFMA acc
typedef __attribute__((ext_vector_type(4))) short short4v;

// bf16 hi/lo split operands (rewritten in full every call -> no stale state)
__device__ unsigned short g_Ahi[(size_t)NROWS * NIN];   // concat(x, dmg) hi
__device__ unsigned short g_Alo[(size_t)NROWS * NIN];   // concat(x, dmg) lo
__device__ unsigned short g_Bhi[NBS * NIN];             // D-folded W12 hi
__device__ unsigned short g_Blo[NBS * NIN];             // D-folded W12 lo

static __device__ __forceinline__ unsigned short f2bf(float v) {
    __hip_bfloat16 h = __float2bfloat16(v);
    return *reinterpret_cast<unsigned short*>(&h);
}
static __device__ __forceinline__ float bf2f(unsigned short u) {
    __hip_bfloat16 h; *reinterpret_cast<unsigned short*>(&h) = u;
    return __bfloat162float(h);
}

// ---------------------------------------------------------------------------
// K0: fold plane-stress D into W12 and split to bf16 hi/lo.
// ---------------------------------------------------------------------------
__global__ __launch_bounds__(256) void k0_w12(const float* __restrict__ W12)
{
    const int idx = blockIdx.x * 256 + threadIdx.x;   // < 384*192 = 73728
    const int r = idx / NIN, i = idx - r * NIN;
    const int p = r / 3, j = r - 3 * p;
    const float* w = W12 + (size_t)(3 * p) * NIN;
    float v;
    if (j == 0)      v = C11 * w[i]           + C12 * w[NIN + i];
    else if (j == 1) v = C12 * w[i]           + C11 * w[NIN + i];
    else             v = C33 * w[2 * NIN + i];
    unsigned short h = f2bf(v);
    g_Bhi[idx] = h;
    g_Blo[idx] = f2bf(v - bf2f(h));
}

// ---------------------------------------------------------------------------
// KX: split x (fp32) into bf16 hi/lo -> cols 0..127 of the A operand buffers.
// ---------------------------------------------------------------------------
__global__ __launch_bounds__(256) void kx_split(const float* __restrict__ x)
{
    const int idx = blockIdx.x * 256 + threadIdx.x;   // NROWS*32
    const int row = idx >> 5, c4 = (idx & 31) * 4;
    float4 v = *(const float4*)(x + (size_t)row * NF + c4);
    float vv[4] = {v.x, v.y, v.z, v.w};
    short4v hv, lv;
#pragma unroll
    for (int i = 0; i < 4; ++i) {
        unsigned short h = f2bf(vv[i]);
        hv[i] = (short)h;
        lv[i] = (short)f2bf(vv[i] - bf2f(h));
    }
    const size_t o = (size_t)row * NIN + c4;
    *(short4v*)(g_Ahi + o) = hv;
    *(short4v*)(g_Alo + o) = lv;
}

// ---------------------------------------------------------------------------
// K1: jumps = leaky_relu(x @ W11^T + b11); d_new from pairs. fp32, unchanged.
// ---------------------------------------------------------------------------
__global__ __launch_bounds__(256, 2) void k1_fc11(
    const float* __restrict__ x, const float* __restrict__ W11,
    const float* __restrict__ b11, float* __restrict__ dnew)
{
    __shared__ float As[16][132];
    __shared__ float Bs[16][128];
    const int tid = threadIdx.x;
    const int row0 = blockIdx.x * 128;
    const int tx = tid & 15, ty = tid >> 4;

    float acc[8][8];
#pragma unroll
    for (int i = 0; i < 8; ++i)
#pragma unroll
        for (int j = 0; j < 8; ++j) acc[i][j] = 0.0f;

    const int lr = tid >> 2;
    const int lk = (tid & 3) * 4;
    const int bn = tid >> 1;
    const int bk = (tid & 1) * 8;

    for (int kc = 0; kc < 8; ++kc) {
        const int k0 = kc * 16;
        float4 a0 = *(const float4*)(x + (size_t)(row0 + lr) * NF + k0 + lk);
        float4 a1 = *(const float4*)(x + (size_t)(row0 + lr + 64) * NF + k0 + lk);
        float4 w0 = *(const float4*)(W11 + (size_t)bn * NF + k0 + bk);
        float4 w1 = *(const float4*)(W11 + (size_t)bn * NF + k0 + bk + 4);
        __syncthreads();
        As[lk+0][lr] = a0.x; As[lk+1][lr] = a0.y; As[lk+2][lr] = a0.z; As[lk+3][lr] = a0.w;
        As[lk+0][lr+64] = a1.x; As[lk+1][lr+64] = a1.y; As[lk+2][lr+64] = a1.z; As[lk+3][lr+64] = a1.w;
        Bs[bk+0][bn] = w0.x; Bs[bk+1][bn] = w0.y; Bs[bk+2][bn] = w0.z; Bs[bk+3][bn] = w0.w;
        Bs[bk+4][bn] = w1.x; Bs[bk+5][bn] = w1.y; Bs[bk+6][bn] = w1.z; Bs[bk+7][bn] = w1.w;
        __syncthreads();
#pragma unroll
        for (int k = 0; k < 16; ++k) {
            float4 av0 = *(const float4*)&As[k][8*ty];
            float4 av1 = *(const float4*)&As[k][8*ty+4];
            float4 bv0 = *(const float4*)&Bs[k][8*tx];
            float4 bv1 = *(const float4*)&Bs[k][8*tx+4];
            float a[8] = {av0.x,av0.y,av0.z,av0.w,av1.x,av1.y,av1.z,av1.w};
            float b[8] = {bv0.x,bv0.y,bv0.z,bv0.w,bv1.x,bv1.y,bv1.z,bv1.w};
#pragma unroll
            for (int i = 0; i < 8; ++i)
#pragma unroll
                for (int j = 0; j < 8; ++j)
                    acc[i][j] = fmaf(a[i], b[j], acc[i][j]);
        }
    }

#pragma unroll
    for (int i = 0; i < 8; ++i) {
        const int row = row0 + 8*ty + i;
        float dnv[4];
#pragma unroll
        for (int jp = 0; jp < 4; ++jp) {
            float z0 = acc[i][2*jp]   + b11[8*tx + 2*jp];
            float z1 = acc[i][2*jp+1] + b11[8*tx + 2*jp+1];
            float jn = fmaxf(z0, 0.0f);
            float js = (z1 > 0.0f) ? z1 : 0.01f * z1;
            float delta = sqrtf(jn*jn + js*js + 1e-12f);
            float dn = 0.1f * (delta - 0.01f) / (fmaxf(delta, 1e-12f) * 0.09f);
            dnv[jp] = fminf(fmaxf(dn, 0.0f), 1.0f);
        }
        float4 dv; dv.x = dnv[0]; dv.y = dnv[1]; dv.z = dnv[2]; dv.w = dnv[3];
        *(float4*)(dnew + (size_t)row * NCOH + 4*tx) = dv;
    }
}

// ---------------------------------------------------------------------------
// K2: cummax over t; emit dmg as bf16 hi/lo into cols 128..191 of A buffers.
// ---------------------------------------------------------------------------
__global__ __launch_bounds__(64) void k2_cummax(const float* __restrict__ d)
{
    const int b = blockIdx.x;          // one batch per block
    const int c = threadIdx.x;         // 0..63
    const float* p = d + (size_t)b * NT * NCOH + c;
    unsigned short* ah = g_Ahi + (size_t)b * NT * NIN + NF + c;
    unsigned short* al = g_Alo + (size_t)b * NT * NIN + NF + c;

    float buf[8];
#pragma unroll
    for (int u = 0; u < 8; ++u) buf[u] = p[(size_t)u * NCOH];

    float m = 0.0f;
#pragma unroll 8
    for (int t = 0; t < NT - 8; ++t) {
        const int sl = t & 7;
        float v = buf[sl];
        buf[sl] = p[(size_t)(t + 8) * NCOH];
        m = fmaxf(m, v);
        unsigned short h = f2bf(m);
        ah[(size_t)t * NIN] = h;
        al[(size_t)t * NIN] = f2bf(m - bf2f(h));
    }
#pragma unroll
    for (int t = NT - 8; t < NT; ++t) {
        m = fmaxf(m, buf[t & 7]);
        unsigned short h = f2bf(m);
        ah[(size_t)t * NIN] = h;
        al[(size_t)t * NIN] = f2bf(m - bf2f(h));
    }
}

// ---------------------------------------------------------------------------
// K3: sig_tr = A @ B^T via bf16x3 MFMA (Ahi*Bhi + Ahi*Blo + Alo*Bhi, K=576).
// R7: NO LDS, NO BARRIERS — all-register fragment GEMM. Each wave loads its
// own A/B fragments global->VGPR (dwordx4, per-lane offset VGPR + scalar base
// + imm kb), double-buffered one chunk ahead, 18 chunks fully unrolled.
// R6 lesson: LDS port + bank conflicts + per-chunk barrier was the wall;
// K=576 is too small to amortize any staging pipeline. B (294 KB) is
// L2-resident; A re-reads are L3-absorbed.
// ---------------------------------------------------------------------------
__global__ __launch_bounds__(256) void k3_mfma(float* __restrict__ sig)
{
    const int tid = threadIdx.x;
    const int lane = tid & 63, w = tid >> 6;
    const int m0 = blockIdx.y * 128;
    const int n0 = blockIdx.x * 128;
    const int wm = (w >> 1) * 64, wn = (w & 1) * 64;
    const int fr = lane & 15, fq = lane >> 4;

    // per-lane fragment byte-offsets (row * NIN + fq*8 elements) * 2 bytes
    unsigned aoff[4], boff[4];
#pragma unroll
    for (int i = 0; i < 4; ++i) {
        aoff[i] = (unsigned)(((m0 + wm + i * 16 + fr) * NIN + fq * 8) * 2);
        boff[i] = (unsigned)(((n0 + wn + i * 16 + fr) * NIN + fq * 8) * 2);
    }
    const char* Ahi = (const char*)g_Ahi;
    const char* Alo = (const char*)g_Alo;
    const char* Bhi = (const char*)g_Bhi;
    const char* Blo = (const char*)g_Blo;

    f32x4 acc[4][4];
#pragma unroll
    for (int mi = 0; mi < 4; ++mi)
#pragma unroll
        for (int ni = 0; ni < 4; ++ni) acc[mi][ni] = (f32x4){0.f, 0.f, 0.f, 0.f};

    bf16x8 a[2][4], b[2][4];
    // chunk c: seg = c/6 (A: hi,hi,lo; B: hi,lo,hi), kb byte off = (c%6)*64
#pragma unroll
    for (int i = 0; i < 4; ++i) {
        a[0][i] = *(const bf16x8*)(Ahi + aoff[i]);
        b[0][i] = *(const bf16x8*)(Bhi + boff[i]);
    }

#pragma unroll
    for (int c = 0; c < 18; ++c) {
        const int cur = c & 1, nxt = cur ^ 1;
        if (c + 1 < 18) {
            const int c1 = c + 1;
            const char* Ab = (c1 / 6 == 2) ? Alo : Ahi;
            const char* Bb = (c1 / 6 == 1) ? Blo : Bhi;
            const int kb = (c1 % 6) * 64;     // byte offset, fits 13-bit imm
#pragma unroll
            for (int i = 0; i < 4; ++i) {
                a[nxt][i] = *(const bf16x8*)(Ab + aoff[i] + kb);
                b[nxt][i] = *(const bf16x8*)(Bb + boff[i] + kb);
            }
        }
#pragma unroll
        for (int mi = 0; mi < 4; ++mi)
#pragma unroll
            for (int ni = 0; ni < 4; ++ni)
                acc[mi][ni] = __builtin_amdgcn_mfma_f32_16x16x32_bf16(
                    a[cur][mi], b[cur][ni], acc[mi][ni], 0, 0, 0);
    }

    // epilogue: C/D layout col=lane&15, row=(lane>>4)*4+reg  [m89-verified]
    const int er = fq * 4, ec = fr;
#pragma unroll
    for (int mi = 0; mi < 4; ++mi)
#pragma unroll
        for (int ni = 0; ni < 4; ++ni)
#pragma unroll
            for (int r = 0; r < 4; ++r)
                sig[(size_t)(m0 + wm + mi * 16 + er + r) * NBS + (n0 + wn + ni * 16 + ec)]
                    = acc[mi][ni][r];
}

// ---------------------------------------------------------------------------
// K4: radial-return ep scan, scaled stress written back in place.
// depth-16 circular register prefetch.
// ---------------------------------------------------------------------------
__global__ __launch_bounds__(128) void k4_plast(float* __restrict__ sig)
{
    const int b = blockIdx.x;          // one batch per block
    const int p = threadIdx.x;         // 0..127 chain
    float* s = sig + (size_t)b * NT * NBS + 3 * p;

    float px[16], py[16], pz[16];
#pragma unroll
    for (int u = 0; u < 16; ++u) {
        const float* sp = s + (size_t)u * NBS;
        px[u] = sp[0]; py[u] = sp[1]; pz[u] = sp[2];
    }

    float ep = 0.0f;
#pragma unroll 16
    for (int t = 0; t < NT - 16; ++t) {
        const int sl = t & 15;
        float sxx = px[sl], syy = py[sl], txy = pz[sl];
        {
            const float* sp = s + (size_t)(t + 16) * NBS;
            px[sl] = sp[0]; py[sl] = sp[1]; pz[sl] = sp[2];
        }
        float seq = sqrtf(sxx*sxx - sxx*syy + syy*syy + 3.0f*txy*txy + 1e-12f);
        float fy = seq - (10.0f + 100.0f * ep);
        float dep = (fy > 0.0f) ? (fy / H3G) : 0.0f;
        ep += dep;
        float scale = (fy > 0.0f) ? ((10.0f + 100.0f * ep) / seq) : 1.0f;
        float* op = s + (size_t)t * NBS;
        op[0] = sxx * scale; op[1] = syy * scale; op[2] = txy * scale;
    }
#pragma unroll
    for (int t = NT - 16; t < NT; ++t) {
        const int sl = t & 15;
        float sxx = px[sl], syy = py[sl], txy = pz[sl];
        float seq = sqrtf(sxx*sxx - sxx*syy + syy*syy + 3.0f*txy*txy + 1e-12f);
        float fy = seq - (10.0f + 100.0f * ep);
        float dep = (fy > 0.0f) ? (fy / H3G) : 0.0f;
        ep += dep;
        float scale = (fy > 0.0f) ? ((10.0f + 100.0f * ep) / seq) : 1.0f;
        float* op = s + (size_t)t * NBS;
        op[0] = sxx * scale; op[1] = syy * scale; op[2] = txy * scale;
    }
}

// ---------------------------------------------------------------------------
// K5: out = softplus(sig @ W2^T). Row-per-thread, zero cross-lane ops.
// ---------------------------------------------------------------------------
__global__ __launch_bounds__(256) void k5_out(
    const float* __restrict__ sig, const float* __restrict__ W2,
    float* __restrict__ out)
{
    __shared__ float W2s[6][NBS];
    const int tid = threadIdx.x;
    for (int i = tid; i < 6 * NBS; i += 256) W2s[i / NBS][i % NBS] = W2[i];
    __syncthreads();

    const int row = blockIdx.x * 256 + tid;     // 512 blocks x 256 = NROWS
    const float4* sv = (const float4*)(sig + (size_t)row * NBS);

    float acc[6] = {0, 0, 0, 0, 0, 0};
#pragma unroll 8
    for (int q = 0; q < NBS / 4; ++q) {
        float4 v = sv[q];
#pragma unroll
        for (int o = 0; o < 6; ++o) {
            float4 wv = *(const float4*)&W2s[o][4 * q];
            acc[o] = fmaf(v.x, wv.x, acc[o]);
            acc[o] = fmaf(v.y, wv.y, acc[o]);
            acc[o] = fmaf(v.z, wv.z, acc[o]);
            acc[o] = fmaf(v.w, wv.w, acc[o]);
        }
    }

    float res[6];
#pragma unroll
    for (int o = 0; o < 6; ++o) {
        float z = acc[o];
        res[o] = fmaxf(z, 0.0f) + log1pf(expf(-fabsf(z)));
    }
    float* op = out + (size_t)row * 6;
#pragma unroll
    for (int o = 0; o < 6; ++o) op[o] = res[o];
}

// ---------------------------------------------------------------------------
extern "C" void kernel_launch(void* const* d_in, const int* in_sizes, int n_in,
                              void* d_out, int out_size, void* d_ws, size_t ws_size,
                              hipStream_t stream)
{
    const float* x   = (const float*)d_in[0];
    const float* W11 = (const float*)d_in[1];
    const float* b11 = (const float*)d_in[2];
    const float* W12 = (const float*)d_in[3];
    const float* W2  = (const float*)d_in[4];
    float* out = (float*)d_out;

    // ws layout: dnew [NROWS*64] fp32 (32MB) | sig [NROWS*384] fp32 (192MB)
    float* dnew = (float*)d_ws;
    float* sig  = (float*)((char*)d_ws + (size_t)NROWS * NCOH * sizeof(float));

    k0_w12<<<(NBS * NIN) / 256, 256, 0, stream>>>(W12);
    kx_split<<<(NROWS * 32) / 256, 256, 0, stream>>>(x);
    k1_fc11<<<NROWS / 128, 256, 0, stream>>>(x, W11, b11, dnew);
    k2_cummax<<<NB, 64, 0, stream>>>(dnew);
    k3_mfma<<<dim3(3, NROWS / 128), 256, 0, stream>>>(sig);
    k4_plast<<<NB, 128, 0, stream>>>(sig);
    k5_out<<<NROWS / 256, 256, 0, stream>>>(sig, W2, out);
}